// Round 4
// baseline (12543.890 us; speedup 1.0000x reference)
//
#include <hip/hip_runtime.h>

#define B_ 128
#define T_ 256
#define I_ 512
#define H_ 1024
#define NWG 128

typedef _Float16 f16;
typedef _Float16 v8h __attribute__((ext_vector_type(8)));
typedef _Float16 v4h __attribute__((ext_vector_type(4)));
typedef float v16f __attribute__((ext_vector_type(16)));

__device__ __forceinline__ float fsigmoid(float x) { return 1.0f / (1.0f + __expf(-x)); }
__device__ __forceinline__ float ftanh(float x) { return 1.0f - 2.0f / (__expf(2.0f * x) + 1.0f); }

__device__ __forceinline__ void gl_lds16(const void* g, void* l) {
    __builtin_amdgcn_global_load_lds(
        (const __attribute__((address_space(1))) unsigned int*)g,
        (__attribute__((address_space(3))) unsigned int*)l, 16, 0, 0);
}

// ---------------- conversion kernels ----------------
__global__ void k_f32_to_f16(const float* __restrict__ in, f16* __restrict__ out, int n) {
    int i = blockIdx.x * blockDim.x + threadIdx.x;
    int st = gridDim.x * blockDim.x;
    for (; i < n; i += st) out[i] = (f16)in[i];
}
__global__ void k_bias_sum(const float* __restrict__ a, const float* __restrict__ b,
                           float* __restrict__ o, int n) {
    int i = blockIdx.x * blockDim.x + threadIdx.x;
    int st = gridDim.x * blockDim.x;
    for (; i < n; i += st) o[i] = a[i] + b[i];
}

// ---------------- grid-wide barrier (device-scope, sense-reversing) ----------------
__device__ __forceinline__ void grid_barrier(int* cnt, int* gen) {
    __syncthreads();
    if (threadIdx.x == 0) {
        __threadfence();  // release: flush my WG's stores to coherence point
        int g = __hip_atomic_load(gen, __ATOMIC_RELAXED, __HIP_MEMORY_SCOPE_AGENT);
        int a = __hip_atomic_fetch_add(cnt, 1, __ATOMIC_ACQ_REL, __HIP_MEMORY_SCOPE_AGENT);
        if (a == NWG - 1) {
            __hip_atomic_store(cnt, 0, __ATOMIC_RELAXED, __HIP_MEMORY_SCOPE_AGENT);
            __hip_atomic_store(gen, g + 1, __ATOMIC_RELEASE, __HIP_MEMORY_SCOPE_AGENT);
        } else {
            while (__hip_atomic_load(gen, __ATOMIC_ACQUIRE, __HIP_MEMORY_SCOPE_AGENT) == g)
                __builtin_amdgcn_s_sleep(4);
        }
    }
    __syncthreads();
    __threadfence();  // acquire side: invalidate caches so fresh h is visible
}

// ---------------- persistent LSTM ----------------
// 128 WGs x 512 threads. slot = bx&1 (0: layer0[t], 1: layer1[t-1]), tile = bx>>1.
// Per WG: output tile 128 b x 16 n (x4 gates). 8 waves = 2 n-frags x 4 k-windows.
// Weights VGPR-resident; A (x/h panels) DMA-streamed into LDS chunk streams.
template <int SLOT>
__device__ void run_slot(int tile, const f16* __restrict__ xh,
                         const f16* __restrict__ wi, const f16* __restrict__ wh,
                         const float* __restrict__ bs,
                         f16* __restrict__ h0, f16* __restrict__ h1,
                         float* __restrict__ out, int* bcnt, int* bgen, char* lds)
{
    constexpr int K0 = SLOT ? 1024 : 512;   // input-region width of combined K
    constexpr int KW = SLOT ? 512 : 384;    // per-wave k-window
    constexpr int NR = KW / 64;             // rounds (chunks of 64 k)
    constexpr int NKS = KW / 16;            // MFMA k-steps per wave
    const size_t BH = (size_t)B_ * H_;

    const int tid = threadIdx.x;
    const int wave = tid >> 6;
    const int lane = tid & 63;
    const int l31 = lane & 31, khi = lane >> 5;
    const int nw = wave & 1, kw = wave >> 1;
    const int n0 = tile * 16;

    // ---- load W fragments into registers (once) ----
    const int gcl = nw * 32 + l31;  // tile gate-col 0..63
    const size_t gr = (size_t)(gcl >> 4) * H_ + n0 + (gcl & 15);
    v8h wfrag[NKS];
#pragma unroll
    for (int s = 0; s < NKS; ++s) {
        const int k = kw * KW + s * 16 + khi * 8;
        const f16* p = (k < K0) ? (wi + gr * K0 + k) : (wh + gr * H_ + (k - K0));
        wfrag[s] = *(const v8h*)p;
    }

    float creg[4] = {0.f, 0.f, 0.f, 0.f};
    const int cb = tid >> 2;          // cell-update row b
    const int cn4 = (tid & 3) * 4;    // cell-update n offset (4 cells)

#pragma unroll 1
    for (int t = 0; t <= T_; ++t) {
        grid_barrier(bcnt, bgen);
        if (SLOT == 0 ? (t >= T_) : (t == 0)) continue;
        const int tau = SLOT ? t - 1 : t;

        const f16* srcA; size_t strA;   // k in [0, K0)
        const f16* srcB;                // k in [K0, K), stride H_
        f16* hout;
        if (SLOT == 0) {
            srcA = xh + (size_t)tau * I_;  strA = (size_t)T_ * I_;
            srcB = h0 + (size_t)((tau + 1) & 1) * BH;
            hout = h0 + (size_t)(tau & 1) * BH;
        } else {
            srcA = h0 + (size_t)(tau & 1) * BH;  strA = H_;
            srcB = h1 + (size_t)((tau + 1) & 1) * BH;
            hout = h1 + (size_t)(tau & 1) * BH;
        }

        v16f acc[4] = {};

        auto issue = [&](int r) {
            const int kc = kw * KW + r * 64;
            const f16* base; size_t str; int koff;
            if (kc < K0) { base = srcA; str = strA; koff = kc; }
            else         { base = srcB; str = (size_t)H_; koff = kc - K0; }
            char* dbase = lds + (size_t)(kw * 2 + (r & 1)) * 16384 + nw * 8192;
#pragma unroll
            for (int i = 0; i < 8; ++i) {
                const int rl = nw * 64 + i * 8 + (lane >> 3);
                const int kk = koff + ((((lane & 7) ^ (rl & 7))) << 3);  // pre-swizzled source slot
                gl_lds16(base + (size_t)rl * str + kk, dbase + i * 1024);
            }
        };

        issue(0);
#pragma unroll
        for (int r = 0; r < NR; ++r) {
            asm volatile("s_waitcnt vmcnt(0)" ::: "memory");
            __builtin_amdgcn_s_barrier();
            __builtin_amdgcn_sched_barrier(0);
            if (r + 1 < NR) issue(r + 1);
            const char* sb = lds + (size_t)(kw * 2 + (r & 1)) * 16384;
#pragma unroll
            for (int ks = 0; ks < 4; ++ks) {
                const int qo = (((ks * 2 + khi) ^ (l31 & 7)) << 4);
#pragma unroll
                for (int mf = 0; mf < 4; ++mf) {
                    const v8h a = *(const v8h*)(sb + (mf * 32 + l31) * 128 + qo);
                    acc[mf] = __builtin_amdgcn_mfma_f32_32x32x16_f16(a, wfrag[r * 4 + ks], acc[mf], 0, 0, 0);
                }
            }
        }

        // ---- k-window reduction across waves (LDS tree) ----
        float* fl = (float*)lds;
        __syncthreads();
        if (kw >= 2) {
            const int s = (kw - 2) * 2 + nw;
#pragma unroll
            for (int mf = 0; mf < 4; ++mf)
#pragma unroll
                for (int j = 0; j < 16; ++j)
                    fl[s * 4096 + (mf * 16 + j) * 64 + lane] = acc[mf][j];
        }
        __syncthreads();
        if (kw < 2) {
            const int s = kw * 2 + nw;
#pragma unroll
            for (int mf = 0; mf < 4; ++mf)
#pragma unroll
                for (int j = 0; j < 16; ++j)
                    acc[mf][j] += fl[s * 4096 + (mf * 16 + j) * 64 + lane];
        }
        __syncthreads();
        if (kw == 1) {
#pragma unroll
            for (int mf = 0; mf < 4; ++mf)
#pragma unroll
                for (int j = 0; j < 16; ++j)
                    fl[16384 + nw * 4096 + (mf * 16 + j) * 64 + lane] = acc[mf][j];
        }
        __syncthreads();
        if (kw == 0) {
            float* gf = (float*)(lds + 98304);  // [128][68] padded
#pragma unroll
            for (int mf = 0; mf < 4; ++mf)
#pragma unroll
                for (int j = 0; j < 16; ++j) {
                    const float v = acc[mf][j] + fl[16384 + nw * 4096 + (mf * 16 + j) * 64 + lane];
                    const int br = mf * 32 + (j & 3) + 8 * (j >> 2) + 4 * khi;
                    gf[br * 68 + nw * 32 + l31] = v;
                }
        }
        __syncthreads();

        // ---- fused cell update: 4 cells per thread ----
        {
            const float* gf = (const float*)(lds + 98304);
            const int n = n0 + cn4;
            const float* gi = gf + cb * 68 + cn4;
            const float* gfo = gf + cb * 68 + 16 + cn4;
            const float* gg = gf + cb * 68 + 32 + cn4;
            const float* go = gf + cb * 68 + 48 + cn4;
            const float* bi = bs + n;
            const float* bf = bs + H_ + n;
            const float* bg = bs + 2 * H_ + n;
            const float* bo = bs + 3 * H_ + n;
            v4h hv;
            float yv[4];
#pragma unroll
            for (int j = 0; j < 4; ++j) {
                const float xi = gi[j] + bi[j];
                const float xf = gfo[j] + bf[j];
                const float xg = gg[j] + bg[j];
                const float xo = go[j] + bo[j];
                const float cn = fsigmoid(xf) * creg[j] + fsigmoid(xi) * ftanh(xg);
                const float hn = fsigmoid(xo) * ftanh(cn);
                creg[j] = cn;
                hv[j] = (f16)hn;
                yv[j] = hn;
            }
            *(v4h*)(hout + (size_t)cb * H_ + n) = hv;
            if (SLOT == 1) {
                float* yp = out + ((size_t)cb * T_ + tau) * H_ + n;
                yp[0] = yv[0]; yp[1] = yv[1]; yp[2] = yv[2]; yp[3] = yv[3];
            }
        }
    }
}

__global__ __launch_bounds__(512, 2) void lstm_persist(
    const f16* __restrict__ xh,
    const f16* __restrict__ w0i, const f16* __restrict__ w0h,
    const f16* __restrict__ w1i, const f16* __restrict__ w1h,
    const float* __restrict__ bs0, const float* __restrict__ bs1,
    f16* __restrict__ h0, f16* __restrict__ h1, float* __restrict__ out,
    int* bcnt, int* bgen)
{
    __shared__ __align__(16) char lds[133120];
    const int bx = blockIdx.x;
    const int tile = bx >> 1;
    if ((bx & 1) == 0) run_slot<0>(tile, xh, w0i, w0h, bs0, h0, h1, out, bcnt, bgen, lds);
    else               run_slot<1>(tile, xh, w1i, w1h, bs1, h0, h1, out, bcnt, bgen, lds);
}

// ---------------- fp32 fallback (round-1 verified) ----------------
#define BM 64
#define NT 8

__global__ __launch_bounds__(256) void lstm_step(
    const float* __restrict__ A1, long a1_stride, int K1,
    const float* __restrict__ hprev,
    const float* __restrict__ Wih, const float* __restrict__ Whh,
    const float* __restrict__ bih, const float* __restrict__ bhh,
    float* __restrict__ cbuf, float* __restrict__ hout,
    float* yout, long y_stride)
{
    __shared__ float As[32][66];
    __shared__ float Ws[32][36];
    const int tid = threadIdx.x;
    const int n0 = blockIdx.x * NT;
    const int b0 = blockIdx.y * BM;
    const int tb = tid >> 3;
    const int tc = tid & 7;
    const int lr = tid >> 3;
    const int lk = tid & 7;
    const long wj = (long)(lr >> 3) * H_ + n0 + (lr & 7);
    float acc[2][4] = {{0.f, 0.f, 0.f, 0.f}, {0.f, 0.f, 0.f, 0.f}};
#pragma unroll 1
    for (int ph = 0; ph < 2; ++ph) {
        const float* Ap = (ph == 0) ? A1 : hprev;
        const long as = (ph == 0) ? a1_stride : (long)H_;
        const float* W = (ph == 0) ? Wih : Whh;
        const int K = (ph == 0) ? K1 : H_;
        const float* arow0 = Ap + (long)(b0 + lr) * as + 4 * lk;
        const float* arow1 = Ap + (long)(b0 + lr + 32) * as + 4 * lk;
        const float* wrow = W + wj * K + 4 * lk;
        float4 ra0 = *(const float4*)(arow0);
        float4 ra1 = *(const float4*)(arow1);
        float4 rw = *(const float4*)(wrow);
        for (int k0 = 0; k0 < K; k0 += 32) {
            __syncthreads();
            {
                const int kk = 4 * lk;
                As[kk + 0][lr] = ra0.x; As[kk + 1][lr] = ra0.y;
                As[kk + 2][lr] = ra0.z; As[kk + 3][lr] = ra0.w;
                As[kk + 0][lr + 32] = ra1.x; As[kk + 1][lr + 32] = ra1.y;
                As[kk + 2][lr + 32] = ra1.z; As[kk + 3][lr + 32] = ra1.w;
                Ws[kk + 0][lr] = rw.x; Ws[kk + 1][lr] = rw.y;
                Ws[kk + 2][lr] = rw.z; Ws[kk + 3][lr] = rw.w;
            }
            __syncthreads();
            const int kn = k0 + 32;
            if (kn < K) {
                ra0 = *(const float4*)(arow0 + kn);
                ra1 = *(const float4*)(arow1 + kn);
                rw = *(const float4*)(wrow + kn);
            }
#pragma unroll
            for (int k = 0; k < 32; ++k) {
                float2 a = *(const float2*)&As[k][2 * tb];
                float4 w = *(const float4*)&Ws[k][4 * tc];
                acc[0][0] = fmaf(a.x, w.x, acc[0][0]);
                acc[0][1] = fmaf(a.x, w.y, acc[0][1]);
                acc[0][2] = fmaf(a.x, w.z, acc[0][2]);
                acc[0][3] = fmaf(a.x, w.w, acc[0][3]);
                acc[1][0] = fmaf(a.y, w.x, acc[1][0]);
                acc[1][1] = fmaf(a.y, w.y, acc[1][1]);
                acc[1][2] = fmaf(a.y, w.z, acc[1][2]);
                acc[1][3] = fmaf(a.y, w.w, acc[1][3]);
            }
        }
    }
    __syncthreads();
    float* gsf = &As[0][0];
#pragma unroll
    for (int bi = 0; bi < 2; ++bi)
#pragma unroll
        for (int ci = 0; ci < 4; ++ci)
            gsf[(2 * tb + bi) * 33 + 4 * tc + ci] = acc[bi][ci];
    __syncthreads();
    const int dn = tid & 7;
    const int bq = tid >> 3;
    const int n = n0 + dn;
#pragma unroll
    for (int s = 0; s < 2; ++s) {
        const int b = bq + 32 * s;
        float xi = gsf[b * 33 + dn] + bih[n] + bhh[n];
        float xf = gsf[b * 33 + 8 + dn] + bih[H_ + n] + bhh[H_ + n];
        float xg = gsf[b * 33 + 16 + dn] + bih[2 * H_ + n] + bhh[2 * H_ + n];
        float xo = gsf[b * 33 + 24 + dn] + bih[3 * H_ + n] + bhh[3 * H_ + n];
        const long idx = (long)(b0 + b) * H_ + n;
        const float c_old = cbuf[idx];
        const float cn = fsigmoid(xf) * c_old + fsigmoid(xi) * ftanh(xg);
        const float hn = fsigmoid(xo) * ftanh(cn);
        cbuf[idx] = cn;
        hout[idx] = hn;
        if (yout) yout[(long)(b0 + b) * y_stride + n] = hn;
    }
}

extern "C" void kernel_launch(void* const* d_in, const int* in_sizes, int n_in,
                              void* d_out, int out_size, void* d_ws, size_t ws_size,
                              hipStream_t stream) {
    const float* x = (const float*)d_in[0];
    const float* Wih0 = (const float*)d_in[1];
    const float* Whh0 = (const float*)d_in[2];
    const float* bih0 = (const float*)d_in[3];
    const float* bhh0 = (const float*)d_in[4];
    const float* Wih1 = (const float*)d_in[5];
    const float* Whh1 = (const float*)d_in[6];
    const float* bih1 = (const float*)d_in[7];
    const float* bhh1 = (const float*)d_in[8];
    float* out = (float*)d_out;

    const size_t BH = (size_t)B_ * H_;
    const size_t NX = (size_t)B_ * T_ * I_;      // 16,777,216
    const size_t NW0I = (size_t)4 * H_ * I_;     // 2,097,152
    const size_t NWH = (size_t)4 * H_ * H_;      // 4,194,304

    const size_t off_xh = 0;
    const size_t off_w0i = off_xh + NX * 2;
    const size_t off_w0h = off_w0i + NW0I * 2;
    const size_t off_w1i = off_w0h + NWH * 2;
    const size_t off_w1h = off_w1i + NWH * 2;
    const size_t off_bs0 = off_w1h + NWH * 2;
    const size_t off_bs1 = off_bs0 + 4 * H_ * 4;
    const size_t off_h0 = off_bs1 + 4 * H_ * 4;
    const size_t off_h1 = off_h0 + 2 * BH * 2;
    const size_t off_bar = off_h1 + 2 * BH * 2;
    const size_t REQ = off_bar + 256;

    char* ws = (char*)d_ws;

    if (ws_size >= REQ) {
        f16* xh = (f16*)(ws + off_xh);
        f16* w0i = (f16*)(ws + off_w0i);
        f16* w0h = (f16*)(ws + off_w0h);
        f16* w1i = (f16*)(ws + off_w1i);
        f16* w1h = (f16*)(ws + off_w1h);
        float* bs0 = (float*)(ws + off_bs0);
        float* bs1 = (float*)(ws + off_bs1);
        f16* h0 = (f16*)(ws + off_h0);
        f16* h1 = (f16*)(ws + off_h1);
        int* bar = (int*)(ws + off_bar);

        // zero h0, h1, barrier vars (contiguous tail)
        hipMemsetAsync(ws + off_h0, 0, REQ - off_h0, stream);

        dim3 cb(256);
        k_f32_to_f16<<<2048, cb, 0, stream>>>(x, xh, (int)NX);
        k_f32_to_f16<<<2048, cb, 0, stream>>>(Wih0, w0i, (int)NW0I);
        k_f32_to_f16<<<2048, cb, 0, stream>>>(Whh0, w0h, (int)NWH);
        k_f32_to_f16<<<2048, cb, 0, stream>>>(Wih1, w1i, (int)NWH);
        k_f32_to_f16<<<2048, cb, 0, stream>>>(Whh1, w1h, (int)NWH);
        k_bias_sum<<<16, cb, 0, stream>>>(bih0, bhh0, bs0, 4 * H_);
        k_bias_sum<<<16, cb, 0, stream>>>(bih1, bhh1, bs1, 4 * H_);

        lstm_persist<<<NWG, 512, 0, stream>>>(xh, w0i, w0h, w1i, w1h, bs0, bs1,
                                              h0, h1, out, bar, bar + 64);
        return;
    }

    // ---------- fp32 fallback ----------
    float* fws = (float*)d_ws;
    float* h0a = fws;
    float* h0b = fws + BH;
    float* c0 = fws + 2 * BH;
    float* h1a = fws + 3 * BH;
    float* h1b = fws + 4 * BH;
    float* c1 = fws + 5 * BH;
    hipMemsetAsync(d_ws, 0, 6 * BH * sizeof(float), stream);

    dim3 grid(H_ / NT, B_ / BM);
    dim3 block(256);
    for (int t = 0; t < T_; ++t) {
        float* h0in = (t & 1) ? h0b : h0a;
        float* h0out = (t & 1) ? h0a : h0b;
        float* h1in = (t & 1) ? h1b : h1a;
        float* h1out = (t & 1) ? h1a : h1b;
        lstm_step<<<grid, block, 0, stream>>>(
            x + (size_t)t * I_, (long)T_ * I_, I_,
            h0in, Wih0, Whh0, bih0, bhh0, c0, h0out, nullptr, 0);
        lstm_step<<<grid, block, 0, stream>>>(
            h0out, (long)H_, H_,
            h1in, Wih1, Whh1, bih1, bhh1, c1, h1out,
            out + (size_t)t * H_, (long)T_ * H_);
    }
}